// Round 1
// baseline (1371.247 us; speedup 1.0000x reference)
//
#include <hip/hip_runtime.h>
#include <cstdint>
#include <cstddef>

// Problem constants
#define B_    8
#define CI    256
#define CT    768
#define NH    8
#define HD    32
#define LQ    77
#define LP    80      // padded key count
#define NSP   13824   // 24^3 spatial tokens
#define TTILE 64
#define NTILE 216     // 13824 / 64

// Workspace layout (float offsets)
#define OFF_WQT  0
#define OFF_WOT  (OFF_WQT + 256*256)
#define OFF_BO   (OFF_WOT + 256*256)
#define OFF_WK   (OFF_BO + 256)
#define OFF_WV   (OFF_WK + 256*768)
#define OFF_KH   (OFF_WV + 256*768)
#define OFF_VH   (OFF_KH + 8*8*77*32)
#define OFF_MASK (OFF_VH + 8*8*77*32)
// total = 840,576 floats ~= 3.4 MB

__device__ inline unsigned short f32_to_bf16(float f) {
    unsigned int u = __float_as_uint(f);
    u += 0x7fffu + ((u >> 16) & 1u);   // round-to-nearest-even
    return (unsigned short)(u >> 16);
}
__device__ inline float bf16_to_f32(unsigned short h) {
    return __uint_as_float(((unsigned int)h) << 16);
}

// ---------------------------------------------------------------------------
// K0a: combined weights  WqT[c][o] = sum_m in_q_w[o][m]*q_proj_w[m][c]
//                        WoT[m][o] = sum_c out_conv_w[o][c]*out_proj_w[c][m]
//                        b_o[o]    = sum_c out_conv_w[o][c]*out_proj_b[c] + out_conv_b[o]
//                        W_k[o][t] = sum_m in_k_w[o][m]*k_proj_w[m][t]   (same for V)
//                        + mask dtype detection & materialization
// ---------------------------------------------------------------------------
__global__ __launch_bounds__(256) void prep_kernel(
    const float* __restrict__ qpw, const float* __restrict__ iqw,
    const float* __restrict__ opw, const float* __restrict__ opb,
    const float* __restrict__ ocw, const float* __restrict__ ocb,
    const float* __restrict__ kpw, const float* __restrict__ ikw,
    const float* __restrict__ vpw, const float* __restrict__ ivw,
    const void*  __restrict__ mask_in, float* __restrict__ ws)
{
    int blk = blockIdx.x, tid = threadIdx.x;
    if (blk < 512) {
        // WqT (blk<256) or WoT (blk<512): one output column per block
        __shared__ float col[256];
        int cc = blk & 255;
        bool isQ = blk < 256;
        const float* pw = isQ ? qpw : opw;
        const float* iw = isQ ? iqw : ocw;
        col[tid] = pw[tid * 256 + cc];
        __syncthreads();
        const float* row = iw + tid * 256;
        float a = 0.f;
        #pragma unroll 4
        for (int m = 0; m < 256; ++m) a = fmaf(row[m], col[m], a);
        ws[(isQ ? OFF_WQT : OFF_WOT) + cc * 256 + tid] = a;
    } else if (blk == 512) {
        float a = ocb[tid];
        const float* row = ocw + tid * 256;
        #pragma unroll 4
        for (int m = 0; m < 256; ++m) a = fmaf(row[m], opb[m], a);
        ws[OFF_BO + tid] = a;
    } else if (blk < 513 + 2 * 768) {
        int j = blk - 513;
        bool isK = j < 768;
        if (!isK) j -= 768;
        int flat = j * 256 + tid;           // flat = o*768 + t
        int o = flat / 768, tt = flat % 768;
        const float* iw = isK ? ikw : ivw;
        const float* pw = isK ? kpw : vpw;
        const float* row = iw + o * 256;
        float a = 0.f;
        #pragma unroll 4
        for (int m = 0; m < 256; ++m) a = fmaf(row[m], pw[m * 768 + tt], a);
        ws[(isK ? OFF_WK : OFF_WV) + flat] = a;
    } else {
        // Mask: detect whether bool arrived as int8 (1B) or int32 (4B).
        // If int32-LE, every byte at index i%4!=0 within the first 616 bytes is 0.
        // If int8, each row's ones-tail guarantees a nonzero byte at i%4!=0.
        __shared__ int s_is8;
        if (tid == 0) s_is8 = 0;
        __syncthreads();
        const unsigned char* m8 = (const unsigned char*)mask_in;
        for (int i = tid; i < B_ * LQ; i += 256)
            if ((i & 3) && m8[i]) atomicExch(&s_is8, 1);
        __syncthreads();
        int is8 = s_is8;
        const int* mi = (const int*)mask_in;
        int* mo = (int*)(ws + OFF_MASK);
        for (int i = tid; i < B_ * LP; i += 256) {
            int b = i / LP, l = i % LP;
            int v = 1;                                   // pad keys masked
            if (l < LQ) v = is8 ? (int)m8[b * LQ + l] : mi[b * LQ + l];
            mo[i] = v ? 1 : 0;
        }
    }
}

// ---------------------------------------------------------------------------
// K0b: kh/vh = x_txt @ W_k^T + b   -> ws as [B][NH][77][32] f32
// Block: (l-group of 8, batch). 8 text rows staged in LDS, thread = out channel.
// ---------------------------------------------------------------------------
__global__ __launch_bounds__(256) void kv_kernel(
    const float* __restrict__ xtxt,
    const float* __restrict__ Wk, const float* __restrict__ Wv,
    const float* __restrict__ ikb, const float* __restrict__ ivb,
    float* __restrict__ khp, float* __restrict__ vhp)
{
    int b = blockIdx.y;
    int l0 = blockIdx.x * 8;
    int lcnt = (LQ - l0 < 8) ? (LQ - l0) : 8;
    __shared__ float xr[8][768];
    for (int idx = threadIdx.x; idx < 8 * 768; idx += 256) {
        int j = idx / 768, tt = idx % 768;
        xr[j][tt] = (j < lcnt) ? xtxt[((size_t)(b * LQ + l0 + j)) * 768 + tt] : 0.f;
    }
    __syncthreads();
    int o = threadIdx.x;
    float ak[8], av[8];
    #pragma unroll
    for (int j = 0; j < 8; ++j) { ak[j] = ikb[o]; av[j] = ivb[o]; }
    const float* wkr = Wk + (size_t)o * 768;
    const float* wvr = Wv + (size_t)o * 768;
    for (int tt = 0; tt < 768; ++tt) {
        float wk = wkr[tt], wv = wvr[tt];
        #pragma unroll
        for (int j = 0; j < 8; ++j) {
            ak[j] = fmaf(wk, xr[j][tt], ak[j]);
            av[j] = fmaf(wv, xr[j][tt], av[j]);
        }
    }
    int h = o >> 5, d = o & 31;
    #pragma unroll
    for (int j = 0; j < 8; ++j) {
        if (j < lcnt) {
            size_t base = ((size_t)(b * NH + h) * LQ + (l0 + j)) * HD + d;
            khp[base] = ak[j];
            vhp[base] = av[j];
        }
    }
}

// ---------------------------------------------------------------------------
// K1: fused  qh-GEMM -> attention -> out-GEMM -> residual, writes r into d_out.
// Block = (64-token tile, batch), 512 threads = 8 waves.
// wave w: qh/out channels [w*32, w*32+32); attention head h = w. lane = token.
// LDS: qh[64][257] f32 (65,792B) + union{ xs bf16 32,768B ; sc f32 20,736B +
//      obuf bf16 34,048B } = 120,576 B total -> 1 block/CU, 2 waves/SIMD.
// ---------------------------------------------------------------------------
__global__ __launch_bounds__(512) void main_kernel(
    const float* __restrict__ x_img, const float* __restrict__ iqb,
    const float* __restrict__ ws, float* __restrict__ rout)
{
    const float* WqT  = ws + OFF_WQT;
    const float* WoT  = ws + OFF_WOT;
    const float* bo   = ws + OFF_BO;
    const float* khp  = ws + OFF_KH;
    const float* vhp  = ws + OFF_VH;
    const int*   maskp = (const int*)(ws + OFF_MASK);

    __shared__ float qh[64 * 257];
    __shared__ alignas(16) char un[54784];
    float*          sc   = (float*)un;                       // [64][81]
    unsigned short* obuf = (unsigned short*)(un + 20736);    // [64][266]
    unsigned short* xs   = (unsigned short*)un;              // [256][64] (aliases sc/obuf)

    int tid = threadIdx.x;
    int by  = blockIdx.y;
    int n0  = blockIdx.x * TTILE;
    int t   = tid & 63;
    int w   = __builtin_amdgcn_readfirstlane(tid >> 6);      // wave id -> SGPR (uniform W addrs)
    int ocb = w * 32;

    const float* xb = x_img + (size_t)by * CI * NSP + n0;

    // ---- stage x tile as bf16 (LDS) ----
    for (int idx = tid; idx < CI * TTILE; idx += 512) {
        int c = idx >> 6, tt = idx & 63;
        xs[idx] = f32_to_bf16(xb[(size_t)c * NSP + tt]);
    }
    __syncthreads();

    // ---- phase 1: qh[t][oc] = sum_c WqT[c][oc] * x[c][t] + iqb[oc] ----
    {
        float acc[32];
        #pragma unroll
        for (int j = 0; j < 32; ++j) acc[j] = iqb[ocb + j];
        #pragma unroll 2
        for (int c = 0; c < 256; ++c) {
            float xv = bf16_to_f32(xs[(c << 6) | t]);
            const float* wr = WqT + c * 256 + ocb;           // 32 consecutive, wave-uniform
            #pragma unroll
            for (int j = 0; j < 32; ++j) acc[j] = fmaf(wr[j], xv, acc[j]);
        }
        #pragma unroll
        for (int j = 0; j < 32; ++j) qh[t * 257 + ocb + j] = acc[j];
    }
    __syncthreads();   // protects xs->sc/obuf union + qh completeness

    // ---- phase 2: attention, head = w, lane = token ----
    {
        const float* kb = khp + (size_t)(by * NH + w) * (LQ * HD);
        const float* vb = vhp + (size_t)(by * NH + w) * (LQ * HD);
        const int* mrow = maskp + by * LP;
        float qreg[32];
        #pragma unroll
        for (int d = 0; d < 32; ++d) qreg[d] = qh[t * 257 + ocb + d];
        float mx = -1e30f;
        for (int l = 0; l < LQ; ++l) {
            float s = -1e30f;
            if (!mrow[l]) {
                const float* kr = kb + l * HD;
                float s0 = 0.f, s1 = 0.f, s2 = 0.f, s3 = 0.f;
                #pragma unroll
                for (int d = 0; d < 32; d += 4) {
                    s0 = fmaf(qreg[d + 0], kr[d + 0], s0);
                    s1 = fmaf(qreg[d + 1], kr[d + 1], s1);
                    s2 = fmaf(qreg[d + 2], kr[d + 2], s2);
                    s3 = fmaf(qreg[d + 3], kr[d + 3], s3);
                }
                s = ((s0 + s1) + (s2 + s3)) * 0.17677669529663687f; // 1/sqrt(32)
            }
            sc[t * 81 + l] = s;
            mx = fmaxf(mx, s);
        }
        float sum = 0.f;
        for (int l = 0; l < LQ; ++l) sum += __expf(sc[t * 81 + l] - mx);
        float inv = 1.f / sum;
        float ao[32];
        #pragma unroll
        for (int d = 0; d < 32; ++d) ao[d] = 0.f;
        for (int l = 0; l < LQ; ++l) {
            float p = __expf(sc[t * 81 + l] - mx) * inv;     // masked: exp(-1e30-mx)=0
            const float* vr = vb + l * HD;
            #pragma unroll
            for (int d = 0; d < 32; ++d) ao[d] = fmaf(p, vr[d], ao[d]);
        }
        #pragma unroll
        for (int d = 0; d < 32; ++d) obuf[t * 266 + ocb + d] = f32_to_bf16(ao[d]);
    }
    __syncthreads();

    // ---- phase 3: out proj + residual; r -> d_out ----
    {
        float facc[32];
        #pragma unroll
        for (int j = 0; j < 32; ++j) facc[j] = bo[ocb + j];
        #pragma unroll 2
        for (int c = 0; c < 256; ++c) {
            float ov = bf16_to_f32(obuf[t * 266 + c]);
            const float* wr = WoT + c * 256 + ocb;
            #pragma unroll
            for (int j = 0; j < 32; ++j) facc[j] = fmaf(wr[j], ov, facc[j]);
        }
        float* rw = rout + (size_t)by * CI * NSP + n0;
        #pragma unroll
        for (int j = 0; j < 32; ++j) {
            int oc = ocb + j;
            rw[(size_t)oc * NSP + t] = facc[j] + xb[(size_t)oc * NSP + t];
        }
    }
}

// ---------------------------------------------------------------------------
// K2: per-(b,c) InstanceNorm + affine + SiLU, in place on d_out.
// ---------------------------------------------------------------------------
__global__ __launch_bounds__(256) void norm_kernel(
    float* __restrict__ rout, const float* __restrict__ nw, const float* __restrict__ nb)
{
    __shared__ float red[8];
    __shared__ float stats[2];
    int blk = blockIdx.x;              // b*256 + c
    int c = blk & 255;
    float* row = rout + (size_t)blk * NSP;
    int tid = threadIdx.x;

    float s = 0.f, s2 = 0.f;
    for (int i = tid; i < NSP; i += 256) {
        float v = row[i];
        s += v;
        s2 = fmaf(v, v, s2);
    }
    #pragma unroll
    for (int off = 32; off > 0; off >>= 1) {
        s  += __shfl_down(s, off);
        s2 += __shfl_down(s2, off);
    }
    int wv = tid >> 6, ln = tid & 63;
    if (ln == 0) { red[wv] = s; red[4 + wv] = s2; }
    __syncthreads();
    if (tid == 0) {
        float S  = red[0] + red[1] + red[2] + red[3];
        float S2 = red[4] + red[5] + red[6] + red[7];
        float mu = S / (float)NSP;
        float var = S2 / (float)NSP - mu * mu;
        stats[0] = mu;
        stats[1] = rsqrtf(var + 1e-5f);
    }
    __syncthreads();
    float mu = stats[0], rstd = stats[1];
    float g  = nw[c] * rstd;
    float b2 = fmaf(-mu, g, nb[c]);    // y = v*g + (nb - mu*g)
    for (int i = tid; i < NSP; i += 256) {
        float v = row[i];
        float y = fmaf(v, g, b2);
        row[i] = y / (1.f + __expf(-y));   // SiLU
    }
}

// ---------------------------------------------------------------------------
extern "C" void kernel_launch(void* const* d_in, const int* in_sizes, int n_in,
                              void* d_out, int out_size, void* d_ws, size_t ws_size,
                              hipStream_t stream) {
    const float* x_img = (const float*)d_in[0];
    const float* x_txt = (const float*)d_in[1];
    const void*  tmask = d_in[2];
    const float* qpw   = (const float*)d_in[3];
    const float* kpw   = (const float*)d_in[4];
    const float* vpw   = (const float*)d_in[5];
    const float* iqw   = (const float*)d_in[6];
    const float* iqb   = (const float*)d_in[7];
    const float* ikw   = (const float*)d_in[8];
    const float* ikb   = (const float*)d_in[9];
    const float* ivw   = (const float*)d_in[10];
    const float* ivb   = (const float*)d_in[11];
    const float* opw   = (const float*)d_in[12];
    const float* opb   = (const float*)d_in[13];
    const float* ocw   = (const float*)d_in[14];
    const float* ocb   = (const float*)d_in[15];
    const float* nw    = (const float*)d_in[16];
    const float* nb    = (const float*)d_in[17];
    float* ws  = (float*)d_ws;
    float* out = (float*)d_out;

    prep_kernel<<<2050, 256, 0, stream>>>(qpw, iqw, opw, opb, ocw, ocb,
                                          kpw, ikw, vpw, ivw, tmask, ws);
    kv_kernel<<<dim3(10, B_), 256, 0, stream>>>(x_txt, ws + OFF_WK, ws + OFF_WV,
                                                ikb, ivb, ws + OFF_KH, ws + OFF_VH);
    main_kernel<<<dim3(NTILE, B_), 512, 0, stream>>>(x_img, iqb, ws, out);
    norm_kernel<<<B_ * CI, 256, 0, stream>>>(out, nw, nb);
}

// Round 2
// 513.536 us; speedup vs baseline: 2.6702x; 2.6702x over previous
//
#include <hip/hip_runtime.h>
#include <cstdint>
#include <cstddef>

// Problem constants
#define B_    8
#define CI    256
#define NH    8
#define HD    32
#define LQ    77
#define LP    80
#define NSP   13824   // 24^3
#define NTILE 216     // 13824 / 64
#define SCALE 0.17677669529663687f   // 1/sqrt(32)

typedef float    float4_ __attribute__((ext_vector_type(4)));
typedef _Float16 half4_  __attribute__((ext_vector_type(4)));

#define MFMA16(a,b,c) __builtin_amdgcn_mfma_f32_16x16x16f16((a),(b),(c),0,0,0)

// Workspace layout (float offsets)
#define OFF_WK   0                       // 256x768 f32
#define OFF_WV   (OFF_WK + 256*768)      // 256x768 f32
#define OFF_BO   (OFF_WV + 256*768)      // 256 f32 (combined out bias)
#define OFF_IQBS (OFF_BO + 256)          // 256 f32 (in_q bias, pre-scaled)
#define OFF_AM   (OFF_IQBS + 256)        // 8x80 f32 additive mask (0 / -1e30)
#define OFF_WQP  (OFF_AM + B_*LP)        // 65536 halves = 32768 f (frag-packed Wq, pre-scaled)
#define OFF_WOP  (OFF_WQP + 32768)       // 65536 halves (frag-packed Wo)
#define OFF_KP   (OFF_WOP + 32768)       // 8*8*5*2*256 halves = 81920 f
#define OFF_VP   (OFF_KP + 81920)        // 8*8*2*5*256 halves = 81920 f
// total = 623744 floats ~= 2.5 MB

// ---------------------------------------------------------------------------
// prep: combined weights -> fragment-packed f16; biases; additive mask.
// Fragment layout (16x16x16f16 A-operand), frag stride 256 halves:
//   frag[kt][ot] : element for A[row=ot*16+(l&15)][k=kt*16+4*(l>>4)+j]
//   stored at (frag*64 + lane)*4 + j
// ---------------------------------------------------------------------------
__global__ __launch_bounds__(256) void prep_kernel(
    const float* __restrict__ qpw, const float* __restrict__ iqw,
    const float* __restrict__ opw, const float* __restrict__ opb,
    const float* __restrict__ ocw, const float* __restrict__ ocb,
    const float* __restrict__ kpw, const float* __restrict__ ikw,
    const float* __restrict__ vpw, const float* __restrict__ ivw,
    const float* __restrict__ iqb,
    const void*  __restrict__ mask_in, float* __restrict__ ws)
{
    int blk = blockIdx.x, tid = threadIdx.x;
    if (blk < 512) {
        // combined Wq[o][c] = sum_m iqw[o][m]*qpw[m][c]  (blk<256, c=blk)
        // combined Wo[o][m] = sum_c ocw[o][c]*opw[c][m]  (blk>=256, m=blk-256)
        __shared__ float col[256];
        int cc = blk & 255;
        bool isQ = blk < 256;
        const float* pw = isQ ? qpw : opw;
        const float* iw = isQ ? iqw : ocw;
        col[tid] = pw[tid * 256 + cc];
        __syncthreads();
        const float* row = iw + tid * 256;
        float a = 0.f;
        #pragma unroll 4
        for (int m = 0; m < 256; ++m) a = fmaf(row[m], col[m], a);
        if (isQ) a *= SCALE;
        _Float16* dst = (_Float16*)(ws + (isQ ? OFF_WQP : OFF_WOP));
        int kt = cc >> 4, ot = tid >> 4;
        int lane = (tid & 15) + 16 * ((cc >> 2) & 3);
        dst[((kt * 16 + ot) * 64 + lane) * 4 + (cc & 3)] = (_Float16)a;
    } else if (blk == 512) {
        // bo = ocw@opb + ocb ; iqbs = iqb*SCALE
        float a = ocb[tid];
        const float* row = ocw + tid * 256;
        #pragma unroll 4
        for (int m = 0; m < 256; ++m) a = fmaf(row[m], opb[m], a);
        ws[OFF_BO + tid] = a;
        ws[OFF_IQBS + tid] = iqb[tid] * SCALE;
    } else if (blk < 513 + 2 * 768) {
        // WK[o][t] = sum_m ikw[o][m]*kpw[m][t]  (f32 intermediates for kv_kernel)
        int j = blk - 513;
        bool isK = j < 768;
        if (!isK) j -= 768;
        int flat = j * 256 + tid;           // flat = o*768 + t
        int o = flat / 768, tt = flat % 768;
        const float* iw = isK ? ikw : ivw;
        const float* pw = isK ? kpw : vpw;
        const float* row = iw + o * 256;
        float a = 0.f;
        #pragma unroll 4
        for (int m = 0; m < 256; ++m) a = fmaf(row[m], pw[m * 768 + tt], a);
        ws[(isK ? OFF_WK : OFF_WV) + flat] = a;
    } else {
        // additive mask, with int8/int32 bool detection
        __shared__ int s_is8;
        if (tid == 0) s_is8 = 0;
        __syncthreads();
        const unsigned char* m8 = (const unsigned char*)mask_in;
        for (int i = tid; i < B_ * LQ; i += 256)
            if ((i & 3) && m8[i]) atomicExch(&s_is8, 1);
        __syncthreads();
        int is8 = s_is8;
        const int* mi = (const int*)mask_in;
        float* mo = ws + OFF_AM;
        for (int i = tid; i < B_ * LP; i += 256) {
            int b = i / LP, l = i % LP;
            int v = 1;                                   // pad keys masked
            if (l < LQ) v = is8 ? (int)m8[b * LQ + l] : mi[b * LQ + l];
            mo[i] = v ? -1e30f : 0.0f;
        }
    }
}

// ---------------------------------------------------------------------------
// kv: kh/vh = x_txt @ WK^T + b, written directly in MFMA fragment layouts:
//   K A-frags: kp[b][h][lt(5)][kd(2)][lane][j] = kh[l=lt*16+(ln&15)][d=kd*16+4*(ln>>4)+j]
//   V A-frags: vp[b][h][dt(2)][lt(5)][lane][j] = vh[l=lt*16+4*(ln>>4)+j][d=dt*16+(ln&15)]
// ---------------------------------------------------------------------------
__global__ __launch_bounds__(256) void kv_kernel(
    const float* __restrict__ xtxt, float* __restrict__ ws,
    const float* __restrict__ ikb, const float* __restrict__ ivb)
{
    const float* Wk = ws + OFF_WK;
    const float* Wv = ws + OFF_WV;
    _Float16* kp = (_Float16*)(ws + OFF_KP);
    _Float16* vp = (_Float16*)(ws + OFF_VP);

    int b = blockIdx.y;
    int l0 = blockIdx.x * 8;
    int lcnt = (LQ - l0 < 8) ? (LQ - l0) : 8;
    __shared__ float xr[8][768];
    for (int idx = threadIdx.x; idx < 8 * 768; idx += 256) {
        int j = idx / 768, tt = idx % 768;
        xr[j][tt] = (j < lcnt) ? xtxt[((size_t)(b * LQ + l0 + j)) * 768 + tt] : 0.f;
    }
    __syncthreads();
    int o = threadIdx.x;
    float ak[8], av[8];
    #pragma unroll
    for (int j = 0; j < 8; ++j) { ak[j] = ikb[o]; av[j] = ivb[o]; }
    const float* wkr = Wk + (size_t)o * 768;
    const float* wvr = Wv + (size_t)o * 768;
    for (int tt = 0; tt < 768; ++tt) {
        float wk = wkr[tt], wv = wvr[tt];
        #pragma unroll
        for (int j = 0; j < 8; ++j) {
            ak[j] = fmaf(wk, xr[j][tt], ak[j]);
            av[j] = fmaf(wv, xr[j][tt], av[j]);
        }
    }
    int h = o >> 5, d = o & 31;
    size_t hb = (size_t)(b * NH + h);
    #pragma unroll
    for (int j = 0; j < 8; ++j) {
        if (j < lcnt) {
            int l = l0 + j;
            int lt = l >> 4;
            // K fragment position
            kp[(hb * 10 + lt * 2 + (d >> 4)) * 256 +
               ((l & 15) + 16 * ((d >> 2) & 3)) * 4 + (d & 3)] = (_Float16)ak[j];
            // V fragment position
            vp[(hb * 10 + (d >> 4) * 5 + lt) * 256 +
               ((d & 15) + 16 * ((l & 15) >> 2)) * 4 + (l & 3)] = (_Float16)av[j];
        }
    }
}

// ---------------------------------------------------------------------------
// main: per (64-token tile, batch): stage X (frag-packed f16 LDS) ->
//  MFMA qh-GEMM -> register-chained attention (QK^T, softmax, PV) ->
//  MFMA out-GEMM -> +residual -> r to d_out.
// Block 256 = 4 waves; wave w owns output-channel range [w*64, w*64+64).
// D-orientation is [channel][token] so D-frags chain as next B-operands.
// LDS: sh0 32KB (X frags, then attn-out frags) + qls 32KB + am 320B.
// ---------------------------------------------------------------------------
__global__ __launch_bounds__(256, 2) void main_kernel(
    const float* __restrict__ x_img, const float* __restrict__ ws,
    float* __restrict__ rout)
{
    const _Float16* wqpk = (const _Float16*)(ws + OFF_WQP);
    const _Float16* wopk = (const _Float16*)(ws + OFF_WOP);
    const _Float16* kpck = (const _Float16*)(ws + OFF_KP);
    const _Float16* vpck = (const _Float16*)(ws + OFF_VP);
    const float* iqbs = ws + OFF_IQBS;
    const float* bog  = ws + OFF_BO;

    __shared__ _Float16 sh0[16384];   // [frag(kt*4+tf)][lane][4] : X, later attn-out
    __shared__ _Float16 qls[16384];   // qh fragments, same layout
    __shared__ float am_s[LP];

    const int tid  = threadIdx.x;
    const int lane = tid & 63;
    const int w    = __builtin_amdgcn_readfirstlane(tid >> 6);
    const int g    = lane >> 4;
    const int li   = lane & 15;
    const int by   = blockIdx.y;
    const int n0   = blockIdx.x * 64;

    const float* xba = x_img + (size_t)by * CI * NSP + n0;
    float*       rba = rout  + (size_t)by * CI * NSP + n0;

    if (tid < LP) am_s[tid] = ws[OFF_AM + by * LP + tid];

    // ---- stage X tile into fragment-packed f16 LDS ----
    // thread handles (c, 8 tokens): coalesced f32 loads, scattered b16 LDS writes
    for (int it = 0; it < 8; ++it) {
        int idx = it * 256 + tid;          // 0..2047
        int c = idx >> 3, hl = idx & 7;    // 8 tokens starting at hl*8
        const float* gp = xba + (size_t)c * NSP + hl * 8;
        float4_ a = *(const float4_*)gp;
        float4_ bvv = *(const float4_*)(gp + 4);
        int kt = c >> 4;
        int lhi = 16 * ((c >> 2) & 3);
        int jj = c & 3;
        #pragma unroll
        for (int u = 0; u < 8; ++u) {
            int t = hl * 8 + u;
            float v = (u < 4) ? a[u] : bvv[u - 4];
            sh0[((kt * 4 + (t >> 4)) * 64 + (t & 15) + lhi) * 4 + jj] = (_Float16)v;
        }
    }
    __syncthreads();

    // ---- phase 1: qh = Wq @ X + iqb  (D rows = q-channel, cols = token) ----
    float4_ acc[4][4];
    #pragma unroll
    for (int of = 0; of < 4; ++of) {
        float bs[4];
        #pragma unroll
        for (int r = 0; r < 4; ++r) bs[r] = iqbs[w * 64 + of * 16 + 4 * g + r];
        #pragma unroll
        for (int tf = 0; tf < 4; ++tf)
            #pragma unroll
            for (int r = 0; r < 4; ++r) acc[of][tf][r] = bs[r];
    }
    for (int kt = 0; kt < 16; ++kt) {
        half4_ bfr[4], afr[4];
        #pragma unroll
        for (int tf = 0; tf < 4; ++tf)
            bfr[tf] = *(const half4_*)&sh0[((kt * 4 + tf) * 64 + lane) * 4];
        #pragma unroll
        for (int of = 0; of < 4; ++of)
            afr[of] = *(const half4_*)&wqpk[((kt * 16 + w * 4 + of) * 64 + lane) * 4];
        #pragma unroll
        for (int of = 0; of < 4; ++of)
            #pragma unroll
            for (int tf = 0; tf < 4; ++tf)
                acc[of][tf] = MFMA16(afr[of], bfr[tf], acc[of][tf]);
    }
    // write qh frags (own-wave region; same-wave ds ordering, no barrier needed)
    #pragma unroll
    for (int of = 0; of < 4; ++of)
        #pragma unroll
        for (int tf = 0; tf < 4; ++tf) {
            half4_ qv;
            #pragma unroll
            for (int r = 0; r < 4; ++r) qv[r] = (_Float16)acc[of][tf][r];
            *(half4_*)&qls[((( w * 4 + of) * 4 + tf) * 64 + lane) * 4] = qv;
        }
    __syncthreads();   // all waves done with sh0 (X) -> reuse as attn-out

    // ---- phase 2: attention; wave w handles heads 2w, 2w+1 ----
    for (int hh = 0; hh < 2; ++hh) {
        const int h = 2 * w + hh;
        half4_ qb[2][4];
        #pragma unroll
        for (int kd = 0; kd < 2; ++kd)
            #pragma unroll
            for (int tf = 0; tf < 4; ++tf)
                qb[kd][tf] = *(const half4_*)&qls[(((h * 2 + kd) * 4 + tf) * 64 + lane) * 4];
        // QK^T: scores[l][t]
        float4_ sc[5][4];
        #pragma unroll
        for (int lt = 0; lt < 5; ++lt)
            #pragma unroll
            for (int tf = 0; tf < 4; ++tf)
                #pragma unroll
                for (int r = 0; r < 4; ++r) sc[lt][tf][r] = 0.f;
        const _Float16* kp = kpck + (size_t)(by * NH + h) * 10 * 256;
        #pragma unroll
        for (int lt = 0; lt < 5; ++lt)
            #pragma unroll
            for (int kd = 0; kd < 2; ++kd) {
                half4_ akf = *(const half4_*)&kp[((lt * 2 + kd) * 64 + lane) * 4];
                #pragma unroll
                for (int tf = 0; tf < 4; ++tf)
                    sc[lt][tf] = MFMA16(akf, qb[kd][tf], sc[lt][tf]);
            }
        // additive mask (also kills pad rows 77..79)
        float mk[5][4];
        #pragma unroll
        for (int lt = 0; lt < 5; ++lt)
            #pragma unroll
            for (int r = 0; r < 4; ++r) mk[lt][r] = am_s[lt * 16 + 4 * g + r];
        #pragma unroll
        for (int lt = 0; lt < 5; ++lt)
            #pragma unroll
            for (int tf = 0; tf < 4; ++tf)
                #pragma unroll
                for (int r = 0; r < 4; ++r) sc[lt][tf][r] += mk[lt][r];
        // softmax over l (rows): per-lane partial over 20 regs, then xor-16/32
        float mx[4], sm[4], inv[4];
        #pragma unroll
        for (int tf = 0; tf < 4; ++tf) {
            float m = -3.0e38f;
            #pragma unroll
            for (int lt = 0; lt < 5; ++lt)
                #pragma unroll
                for (int r = 0; r < 4; ++r) m = fmaxf(m, sc[lt][tf][r]);
            m = fmaxf(m, __shfl_xor(m, 16));
            m = fmaxf(m, __shfl_xor(m, 32));
            mx[tf] = m;
        }
        #pragma unroll
        for (int tf = 0; tf < 4; ++tf) {
            float s = 0.f;
            #pragma unroll
            for (int lt = 0; lt < 5; ++lt)
                #pragma unroll
                for (int r = 0; r < 4; ++r) {
                    float e = __expf(sc[lt][tf][r] - mx[tf]);
                    sc[lt][tf][r] = e;
                    s += e;
                }
            s += __shfl_xor(s, 16);
            s += __shfl_xor(s, 32);
            sm[tf] = s;
            inv[tf] = 1.0f / s;
        }
        // PV: O[d][t] = sum_l V'[d][l] * P[l][t]; P frags = sc frags (chained)
        float4_ oa[2][4];
        #pragma unroll
        for (int dt = 0; dt < 2; ++dt)
            #pragma unroll
            for (int tf = 0; tf < 4; ++tf)
                #pragma unroll
                for (int r = 0; r < 4; ++r) oa[dt][tf][r] = 0.f;
        const _Float16* vp = vpck + (size_t)(by * NH + h) * 10 * 256;
        #pragma unroll
        for (int lt = 0; lt < 5; ++lt) {
            half4_ pl[4];
            #pragma unroll
            for (int tf = 0; tf < 4; ++tf) {
                #pragma unroll
                for (int r = 0; r < 4; ++r) pl[tf][r] = (_Float16)sc[lt][tf][r];
            }
            #pragma unroll
            for (int dt = 0; dt < 2; ++dt) {
                half4_ avf = *(const half4_*)&vp[((dt * 5 + lt) * 64 + lane) * 4];
                #pragma unroll
                for (int tf = 0; tf < 4; ++tf)
                    oa[dt][tf] = MFMA16(avf, pl[tf], oa[dt][tf]);
            }
        }
        // normalize, convert, store attn-out frags to sh0
        #pragma unroll
        for (int dt = 0; dt < 2; ++dt)
            #pragma unroll
            for (int tf = 0; tf < 4; ++tf) {
                half4_ ov;
                #pragma unroll
                for (int r = 0; r < 4; ++r) ov[r] = (_Float16)(oa[dt][tf][r] * inv[tf]);
                *(half4_*)&sh0[(((h * 2 + dt) * 4 + tf) * 64 + lane) * 4] = ov;
            }
    }
    __syncthreads();   // attn-out frags visible to all waves

    // ---- phase 3: r = Wo @ attn_out + bo + x ----
    float4_ fa[4][4];
    #pragma unroll
    for (int of = 0; of < 4; ++of) {
        float bs[4];
        #pragma unroll
        for (int r = 0; r < 4; ++r) bs[r] = bog[w * 64 + of * 16 + 4 * g + r];
        #pragma unroll
        for (int tf = 0; tf < 4; ++tf)
            #pragma unroll
            for (int r = 0; r < 4; ++r) fa[of][tf][r] = bs[r];
    }
    for (int kt = 0; kt < 16; ++kt) {
        half4_ bfr[4], afr[4];
        #pragma unroll
        for (int tf = 0; tf < 4; ++tf)
            bfr[tf] = *(const half4_*)&sh0[((kt * 4 + tf) * 64 + lane) * 4];
        #pragma unroll
        for (int of = 0; of < 4; ++of)
            afr[of] = *(const half4_*)&wopk[((kt * 16 + w * 4 + of) * 64 + lane) * 4];
        #pragma unroll
        for (int of = 0; of < 4; ++of)
            #pragma unroll
            for (int tf = 0; tf < 4; ++tf)
                fa[of][tf] = MFMA16(afr[of], bfr[tf], fa[of][tf]);
    }
    // epilogue: + residual, store r
    #pragma unroll
    for (int of = 0; of < 4; ++of)
        #pragma unroll
        for (int tf = 0; tf < 4; ++tf)
            #pragma unroll
            for (int r = 0; r < 4; ++r) {
                int o = w * 64 + of * 16 + 4 * g + r;
                int t = tf * 16 + li;
                size_t a = (size_t)o * NSP + t;
                rba[a] = fa[of][tf][r] + xba[a];
            }
}

// ---------------------------------------------------------------------------
// norm: per-(b,c) InstanceNorm + affine + SiLU, in place, float4 vectorized.
// ---------------------------------------------------------------------------
__global__ __launch_bounds__(256) void norm_kernel(
    float* __restrict__ rout, const float* __restrict__ nw, const float* __restrict__ nb)
{
    __shared__ float red[8];
    __shared__ float stats[2];
    int blk = blockIdx.x;              // b*256 + c
    int c = blk & 255;
    float* row = rout + (size_t)blk * NSP;
    float4_* row4 = (float4_*)row;
    int tid = threadIdx.x;

    float s = 0.f, s2 = 0.f;
    for (int i = tid; i < NSP / 4; i += 256) {
        float4_ v = row4[i];
        #pragma unroll
        for (int u = 0; u < 4; ++u) { s += v[u]; s2 = fmaf(v[u], v[u], s2); }
    }
    #pragma unroll
    for (int off = 32; off > 0; off >>= 1) {
        s  += __shfl_down(s, off);
        s2 += __shfl_down(s2, off);
    }
    int wv = tid >> 6, ln = tid & 63;
    if (ln == 0) { red[wv] = s; red[4 + wv] = s2; }
    __syncthreads();
    if (tid == 0) {
        float S  = red[0] + red[1] + red[2] + red[3];
        float S2 = red[4] + red[5] + red[6] + red[7];
        float mu = S / (float)NSP;
        float var = S2 / (float)NSP - mu * mu;
        stats[0] = mu;
        stats[1] = rsqrtf(var + 1e-5f);
    }
    __syncthreads();
    float mu = stats[0], rstd = stats[1];
    float gg  = nw[c] * rstd;
    float b2 = fmaf(-mu, gg, nb[c]);
    for (int i = tid; i < NSP / 4; i += 256) {
        float4_ v = row4[i];
        #pragma unroll
        for (int u = 0; u < 4; ++u) {
            float y = fmaf(v[u], gg, b2);
            v[u] = y / (1.f + __expf(-y));
        }
        row4[i] = v;
    }
}

// ---------------------------------------------------------------------------
extern "C" void kernel_launch(void* const* d_in, const int* in_sizes, int n_in,
                              void* d_out, int out_size, void* d_ws, size_t ws_size,
                              hipStream_t stream) {
    const float* x_img = (const float*)d_in[0];
    const float* x_txt = (const float*)d_in[1];
    const void*  tmask = d_in[2];
    const float* qpw   = (const float*)d_in[3];
    const float* kpw   = (const float*)d_in[4];
    const float* vpw   = (const float*)d_in[5];
    const float* iqw   = (const float*)d_in[6];
    const float* iqb   = (const float*)d_in[7];
    const float* ikw   = (const float*)d_in[8];
    const float* ikb   = (const float*)d_in[9];
    const float* ivw   = (const float*)d_in[10];
    const float* ivb   = (const float*)d_in[11];
    const float* opw   = (const float*)d_in[12];
    const float* opb   = (const float*)d_in[13];
    const float* ocw   = (const float*)d_in[14];
    const float* ocb   = (const float*)d_in[15];
    const float* nw    = (const float*)d_in[16];
    const float* nb    = (const float*)d_in[17];
    float* ws  = (float*)d_ws;
    float* out = (float*)d_out;

    prep_kernel<<<2050, 256, 0, stream>>>(qpw, iqw, opw, opb, ocw, ocb,
                                          kpw, ikw, vpw, ivw, iqb, tmask, ws);
    kv_kernel<<<dim3(10, B_), 256, 0, stream>>>(x_txt, ws, ikb, ivb);
    main_kernel<<<dim3(NTILE, B_), 256, 0, stream>>>(x_img, ws, out);
    norm_kernel<<<B_ * CI, 256, 0, stream>>>(out, nw, nb);
}

// Round 4
// 504.599 us; speedup vs baseline: 2.7175x; 1.0177x over previous
//
#include <hip/hip_runtime.h>
#include <cstdint>
#include <cstddef>

// Problem constants
#define B_    8
#define CI    256
#define NH    8
#define HD    32
#define LQ    77
#define LP    80
#define NSP   13824   // 24^3
#define NTILE 216     // 13824 / 64
#define SCALE 0.17677669529663687f   // 1/sqrt(32)

typedef float    float4_ __attribute__((ext_vector_type(4)));
typedef _Float16 half4_  __attribute__((ext_vector_type(4)));

#define MFMA16(a,b,c) __builtin_amdgcn_mfma_f32_16x16x16f16((a),(b),(c),0,0,0)

// Workspace layout (float offsets)
// Fragment conventions (verified in R2 passing kernel):
//  A-frag of M[row][k]:  a[j] at lane = M[row = lane&15][k = 4*(lane>>4)+j]
//  B-frag of M[k][col]:  b[j] at lane = M[k = 4*(lane>>4)+j][col = lane&15]
//  D-frag:               d[r] at lane = D[row = 4*(lane>>4)+r][col = lane&15]
//  => D-frag of T^T  ==  A-frag of T   (same lane mapping)
//  => A-frag of M    ==  B-frag of M^T
#define OFF_WQP  0                        // Wq A-frags [16kt][16ot][64][4] f16 (pre-scaled)
#define OFF_WOP  32768                    // Wo A-frags [16][16][64][4] f16
#define OFF_WKP  65536                    // Wk A-frags [48kt][16ot][64][4] f16
#define OFF_WVP  163840                   // Wv A-frags [48][16][64][4] f16
#define OFF_KP   262144                   // K  A-frags [B][H][5lt][2kd][64][4] f16
#define OFF_VP   344064                   // V' A-frags [B][H][2dt][5lt][64][4] f16
#define OFF_BO   425984                   // 256 f32 combined out bias
#define OFF_IQBS 426240                   // 256 f32 in_q bias * SCALE
#define OFF_AM   426496                   // 8x80 f32 additive mask
#define OFF_STAT 427136                   // 8x256x2 f32 (sum, sumsq) -- zeroed by prep
// total 431232 floats ~= 1.7 MB

// ---------------------------------------------------------------------------
// prep0: biases, additive mask (with bool int8/int32 detection), zero stats.
// ---------------------------------------------------------------------------
__global__ __launch_bounds__(256) void prep_kernel(
    const float* __restrict__ opb, const float* __restrict__ ocw,
    const float* __restrict__ ocb, const float* __restrict__ iqb,
    const void*  __restrict__ mask_in, float* __restrict__ ws)
{
    int blk = blockIdx.x, tid = threadIdx.x;
    if (blk == 0) {
        float a = ocb[tid];
        const float* row = ocw + tid * 256;
        #pragma unroll 4
        for (int m = 0; m < 256; ++m) a = fmaf(row[m], opb[m], a);
        ws[OFF_BO + tid] = a;
        ws[OFF_IQBS + tid] = iqb[tid] * SCALE;
    } else if (blk == 1) {
        __shared__ int s_is8;
        if (tid == 0) s_is8 = 0;
        __syncthreads();
        const unsigned char* m8 = (const unsigned char*)mask_in;
        for (int i = tid; i < B_ * LQ; i += 256)
            if ((i & 3) && m8[i]) atomicExch(&s_is8, 1);
        __syncthreads();
        int is8 = s_is8;
        const int* mi = (const int*)mask_in;
        float* mo = ws + OFF_AM;
        for (int i = tid; i < B_ * LP; i += 256) {
            int b = i / LP, l = i % LP;
            int v = 1;
            if (l < LQ) v = is8 ? (int)m8[b * LQ + l] : mi[b * LQ + l];
            mo[i] = v ? -1e30f : 0.0f;
        }
    } else {
        for (int i = tid; i < B_ * CI * 2; i += 256) ws[OFF_STAT + i] = 0.f;
    }
}

// ---------------------------------------------------------------------------
// wcomb: combined weights via MFMA, output directly in A-frag f16 layout.
//   T[o][k] = sum_m iw[o][m] * pw[m][k];  D = T^T computed as A~(pw^T) x B~(iw^T)
//   D-frag of T^T == A-frag of T -> contiguous half4 store.
// Segments: Wq(16 blk), Wo(16), Wk(48), Wv(48). Block = 4ct x 4ot frags.
// ---------------------------------------------------------------------------
__global__ __launch_bounds__(256) void wcomb_kernel(
    const float* __restrict__ qpw, const float* __restrict__ iqw,
    const float* __restrict__ opw, const float* __restrict__ ocw,
    const float* __restrict__ kpw, const float* __restrict__ ikw,
    const float* __restrict__ vpw, const float* __restrict__ ivw,
    float* __restrict__ ws)
{
    int blk = blockIdx.x, tid = threadIdx.x;
    int lane = tid & 63, w = tid >> 6, g = lane >> 4, li = lane & 15;

    const float *iw, *pw; _Float16* dst; int pstride, ctb, otb; float scale = 1.f;
    if (blk < 16) {
        iw = iqw; pw = qpw; pstride = 256; dst = (_Float16*)(ws + OFF_WQP);
        ctb = blk >> 2; otb = blk & 3; scale = SCALE;
    } else if (blk < 32) {
        int j = blk - 16;
        iw = ocw; pw = opw; pstride = 256; dst = (_Float16*)(ws + OFF_WOP);
        ctb = j >> 2; otb = j & 3;
    } else if (blk < 80) {
        int j = blk - 32;
        iw = ikw; pw = kpw; pstride = 768; dst = (_Float16*)(ws + OFF_WKP);
        ctb = j >> 2; otb = j & 3;
    } else {
        int j = blk - 80;
        iw = ivw; pw = vpw; pstride = 768; dst = (_Float16*)(ws + OFF_WVP);
        ctb = j >> 2; otb = j & 3;
    }
    int ct = ctb * 4 + w;      // output-k tile handled by this wave

    float4_ acc[4];
    #pragma unroll
    for (int i = 0; i < 4; ++i)
        #pragma unroll
        for (int r = 0; r < 4; ++r) acc[i][r] = 0.f;

    for (int mt = 0; mt < 16; ++mt) {
        half4_ ah;
        #pragma unroll
        for (int j = 0; j < 4; ++j)
            ah[j] = (_Float16)pw[(size_t)(mt * 16 + 4 * g + j) * pstride + ct * 16 + li];
        #pragma unroll
        for (int i = 0; i < 4; ++i) {
            int o = (otb * 4 + i) * 16 + li;
            float4_ bw = *(const float4_*)&iw[(size_t)o * 256 + mt * 16 + 4 * g];
            half4_ bh;
            #pragma unroll
            for (int j = 0; j < 4; ++j) bh[j] = (_Float16)bw[j];
            acc[i] = MFMA16(ah, bh, acc[i]);
        }
    }
    #pragma unroll
    for (int i = 0; i < 4; ++i) {
        half4_ oh;
        #pragma unroll
        for (int r = 0; r < 4; ++r) oh[r] = (_Float16)(acc[i][r] * scale);
        *(half4_*)&dst[((size_t)(ct * 16 + otb * 4 + i) * 64 + lane) * 4] = oh;
    }
}

// ---------------------------------------------------------------------------
// kv: kh/vh via MFMA directly into K/V fragment layouts.
//   K-part: D = Wk x X^T (rows=o, cols=l) -> A-frag of kh[l][d]
//   V-part: D = X x Wv^T (rows=l, cols=o) -> A-frag of vh^T = V'[d][l]
// Grid: (b, part) = 16 blocks, 4 waves; wave w -> ot in [4w, 4w+4).
// ---------------------------------------------------------------------------
__global__ __launch_bounds__(256) void kv_kernel(
    const float* __restrict__ xtxt, float* __restrict__ ws,
    const float* __restrict__ ikb, const float* __restrict__ ivb)
{
    const _Float16* wkA = (const _Float16*)(ws + OFF_WKP);
    const _Float16* wvA = (const _Float16*)(ws + OFF_WVP);
    _Float16* kp = (_Float16*)(ws + OFF_KP);
    _Float16* vp = (_Float16*)(ws + OFF_VP);

    int b = blockIdx.x >> 1, part = blockIdx.x & 1;
    int tid = threadIdx.x, lane = tid & 63, w = tid >> 6, g = lane >> 4, li = lane & 15;

    float4_ acc[4][5];
    if (part == 0) {
        #pragma unroll
        for (int i = 0; i < 4; ++i) {
            float4_ bias = *(const float4_*)&ikb[(w * 4 + i) * 16 + 4 * g];
            #pragma unroll
            for (int lt = 0; lt < 5; ++lt) acc[i][lt] = bias;
        }
    } else {
        #pragma unroll
        for (int i = 0; i < 4; ++i) {
            float bv = ivb[(w * 4 + i) * 16 + li];
            #pragma unroll
            for (int lt = 0; lt < 5; ++lt)
                #pragma unroll
                for (int r = 0; r < 4; ++r) acc[i][lt][r] = bv;
        }
    }

    for (int kt = 0; kt < 48; ++kt) {
        half4_ xh[5];
        #pragma unroll
        for (int lt = 0; lt < 5; ++lt) {
            int l = lt * 16 + li;
            float4_ xv = {0.f, 0.f, 0.f, 0.f};
            if (l < LQ)
                xv = *(const float4_*)&xtxt[(size_t)(b * LQ + l) * 768 + kt * 16 + 4 * g];
            #pragma unroll
            for (int j = 0; j < 4; ++j) xh[lt][j] = (_Float16)xv[j];
        }
        if (part == 0) {
            #pragma unroll
            for (int i = 0; i < 4; ++i) {
                half4_ aw = *(const half4_*)&wkA[((size_t)(kt * 16 + w * 4 + i) * 64 + lane) * 4];
                #pragma unroll
                for (int lt = 0; lt < 5; ++lt)
                    acc[i][lt] = MFMA16(aw, xh[lt], acc[i][lt]);
            }
        } else {
            #pragma unroll
            for (int i = 0; i < 4; ++i) {
                half4_ bw = *(const half4_*)&wvA[((size_t)(kt * 16 + w * 4 + i) * 64 + lane) * 4];
                #pragma unroll
                for (int lt = 0; lt < 5; ++lt)
                    acc[i][lt] = MFMA16(xh[lt], bw, acc[i][lt]);
            }
        }
    }

    #pragma unroll
    for (int i = 0; i < 4; ++i) {
        int ot = w * 4 + i, h = ot >> 1;
        size_t hb = (size_t)(b * NH + h) * 10;
        #pragma unroll
        for (int lt = 0; lt < 5; ++lt) {
            half4_ oh;
            #pragma unroll
            for (int r = 0; r < 4; ++r) oh[r] = (_Float16)acc[i][lt][r];
            if (part == 0) {
                int kd = ot & 1;
                *(half4_*)&kp[(hb + lt * 2 + kd) * 256 + lane * 4] = oh;
            } else {
                int dt = ot & 1;
                *(half4_*)&vp[(hb + dt * 5 + lt) * 256 + lane * 4] = oh;
            }
        }
    }
}

// ---------------------------------------------------------------------------
// main: stage X frags -> qh GEMM (regs) -> attention (reg-chained, tf-split)
//  -> out GEMM -> LDS-staged coalesced epilogue (residual + partial stats).
// Block 256 = 4 waves, wave w owns output channels [w*64, w*64+64).
// LDS: sh0 32KB (X frags / attn-out frags / f16 epilogue staging) + am.
// ---------------------------------------------------------------------------
__global__ __launch_bounds__(256, 3) void main_kernel(
    const float* __restrict__ x_img, const float* __restrict__ ws,
    float* __restrict__ rout, float* __restrict__ stat)
{
    const _Float16* wqpk = (const _Float16*)(ws + OFF_WQP);
    const _Float16* wopk = (const _Float16*)(ws + OFF_WOP);
    const _Float16* kpck = (const _Float16*)(ws + OFF_KP);
    const _Float16* vpck = (const _Float16*)(ws + OFF_VP);
    const float* iqbs = ws + OFF_IQBS;
    const float* bog  = ws + OFF_BO;

    __shared__ _Float16 sh0[16384];
    __shared__ float am_s[LP];

    const int tid  = threadIdx.x;
    const int lane = tid & 63;
    const int w    = __builtin_amdgcn_readfirstlane(tid >> 6);
    const int g    = lane >> 4;
    const int li   = lane & 15;
    const int by   = blockIdx.y;
    const int n0   = blockIdx.x * 64;

    const float* xba = x_img + (size_t)by * CI * NSP + n0;
    float*       rba = rout  + (size_t)by * CI * NSP + n0;

    if (tid < LP) am_s[tid] = ws[OFF_AM + by * LP + tid];

    // ---- stage X tile as B-frags (coalesced scalar loads, half4 LDS writes) ----
    {
        int t = tid & 63, tf_s = t >> 4, tl = t & 15;
        for (int it = 0; it < 16; ++it) {
            int cbase = it * 16 + 4 * w;          // c = cbase + j
            half4_ hv;
            #pragma unroll
            for (int j = 0; j < 4; ++j)
                hv[j] = (_Float16)xba[(size_t)(cbase + j) * NSP + t];
            *(half4_*)&sh0[((it * 4 + tf_s) * 64 + tl + 16 * w) * 4] = hv;
        }
    }
    __syncthreads();

    // ---- phase 1: qh = Wq @ X + iqb; accumulators stay in registers ----
    half4_ qh_h[4][4];
    {
        float4_ acc[4][4];
        #pragma unroll
        for (int of = 0; of < 4; ++of) {
            float4_ bias = *(const float4_*)&iqbs[w * 64 + of * 16 + 4 * g];
            #pragma unroll
            for (int tf = 0; tf < 4; ++tf) acc[of][tf] = bias;
        }
        for (int kt = 0; kt < 16; ++kt) {
            half4_ bfr[4], afr[4];
            #pragma unroll
            for (int tf = 0; tf < 4; ++tf)
                bfr[tf] = *(const half4_*)&sh0[((kt * 4 + tf) * 64 + lane) * 4];
            #pragma unroll
            for (int of = 0; of < 4; ++of)
                afr[of] = *(const half4_*)&wqpk[((size_t)(kt * 16 + w * 4 + of) * 64 + lane) * 4];
            #pragma unroll
            for (int of = 0; of < 4; ++of)
                #pragma unroll
                for (int tf = 0; tf < 4; ++tf)
                    acc[of][tf] = MFMA16(afr[of], bfr[tf], acc[of][tf]);
        }
        #pragma unroll
        for (int of = 0; of < 4; ++of)
            #pragma unroll
            for (int tf = 0; tf < 4; ++tf)
                #pragma unroll
                for (int r = 0; r < 4; ++r)
                    qh_h[of][tf][r] = (_Float16)acc[of][tf][r];
    }
    __syncthreads();   // all waves done reading X frags -> sh0 reusable

    // ---- phase 2: attention, wave w handles heads 2w, 2w+1 (tf-halved) ----
    #pragma unroll
    for (int hh = 0; hh < 2; ++hh) {
        const int h = 2 * w + hh;
        const _Float16* kp = kpck + (size_t)(by * NH + h) * 2560;
        const _Float16* vp = vpck + (size_t)(by * NH + h) * 2560;
        float mk[5][4];
        #pragma unroll
        for (int lt = 0; lt < 5; ++lt)
            #pragma unroll
            for (int r = 0; r < 4; ++r) mk[lt][r] = am_s[lt * 16 + 4 * g + r];
        #pragma unroll
        for (int tfh = 0; tfh < 2; ++tfh) {
            float4_ sc[5][2];
            #pragma unroll
            for (int lt = 0; lt < 5; ++lt)
                #pragma unroll
                for (int t2 = 0; t2 < 2; ++t2)
                    #pragma unroll
                    for (int r = 0; r < 4; ++r) sc[lt][t2][r] = 0.f;
            #pragma unroll
            for (int lt = 0; lt < 5; ++lt)
                #pragma unroll
                for (int kd = 0; kd < 2; ++kd) {
                    half4_ akf = *(const half4_*)&kp[((lt * 2 + kd) * 64 + lane) * 4];
                    #pragma unroll
                    for (int t2 = 0; t2 < 2; ++t2)
                        sc[lt][t2] = MFMA16(akf, qh_h[2 * hh + kd][tfh * 2 + t2], sc[lt][t2]);
                }
            #pragma unroll
            for (int lt = 0; lt < 5; ++lt)
                #pragma unroll
                for (int t2 = 0; t2 < 2; ++t2)
                    #pragma unroll
                    for (int r = 0; r < 4; ++r) sc[lt][t2][r] += mk[lt][r];
            // softmax over l (rows)
            float inv[2];
            #pragma unroll
            for (int t2 = 0; t2 < 2; ++t2) {
                float m = -3.0e38f;
                #pragma unroll
                for (int lt = 0; lt < 5; ++lt)
                    #pragma unroll
                    for (int r = 0; r < 4; ++r) m = fmaxf(m, sc[lt][t2][r]);
                m = fmaxf(m, __shfl_xor(m, 16));
                m = fmaxf(m, __shfl_xor(m, 32));
                float s = 0.f;
                #pragma unroll
                for (int lt = 0; lt < 5; ++lt)
                    #pragma unroll
                    for (int r = 0; r < 4; ++r) {
                        float e = __expf(sc[lt][t2][r] - m);
                        sc[lt][t2][r] = e;
                        s += e;
                    }
                s += __shfl_xor(s, 16);
                s += __shfl_xor(s, 32);
                inv[t2] = 1.0f / s;
            }
            // PV (P frags chained from sc)
            float4_ oa[2][2];
            #pragma unroll
            for (int dt = 0; dt < 2; ++dt)
                #pragma unroll
                for (int t2 = 0; t2 < 2; ++t2)
                    #pragma unroll
                    for (int r = 0; r < 4; ++r) oa[dt][t2][r] = 0.f;
            #pragma unroll
            for (int lt = 0; lt < 5; ++lt) {
                half4_ pl[2];
                #pragma unroll
                for (int t2 = 0; t2 < 2; ++t2)
                    #pragma unroll
                    for (int r = 0; r < 4; ++r) pl[t2][r] = (_Float16)sc[lt][t2][r];
                #pragma unroll
                for (int dt = 0; dt < 2; ++dt) {
                    half4_ avf = *(const half4_*)&vp[((dt * 5 + lt) * 64 + lane) * 4];
                    #pragma unroll
                    for (int t2 = 0; t2 < 2; ++t2)
                        oa[dt][t2] = MFMA16(avf, pl[t2], oa[dt][t2]);
                }
            }
            // normalize + store attn-out frags to sh0
            #pragma unroll
            for (int dt = 0; dt < 2; ++dt)
                #pragma unroll
                for (int t2 = 0; t2 < 2; ++t2) {
                    half4_ ov;
                    #pragma unroll
                    for (int r = 0; r < 4; ++r) ov[r] = (_Float16)(oa[dt][t2][r] * inv[t2]);
                    *(half4_*)&sh0[(((h * 2 + dt) * 4 + tfh * 2 + t2) * 64 + lane) * 4] = ov;
                }
        }
    }
    __syncthreads();

    // ---- phase 3: r_pre = Wo @ attn_out + bo ----
    float4_ fa[4][4];
    #pragma unroll
    for (int of = 0; of < 4; ++of) {
        float4_ bias = *(const float4_*)&bog[w * 64 + of * 16 + 4 * g];
        #pragma unroll
        for (int tf = 0; tf < 4; ++tf) fa[of][tf] = bias;
    }
    for (int kt = 0; kt < 16; ++kt) {
        half4_ bfr[4], afr[4];
        #pragma unroll
        for (int tf = 0; tf < 4; ++tf)
            bfr[tf] = *(const half4_*)&sh0[((kt * 4 + tf) * 64 + lane) * 4];
        #pragma unroll
        for (int of = 0; of < 4; ++of)
            afr[of] = *(const half4_*)&wopk[((size_t)(kt * 16 + w * 4 + of) * 64 + lane) * 4];
        #pragma unroll
        for (int of = 0; of < 4; ++of)
            #pragma unroll
            for (int tf = 0; tf < 4; ++tf)
                fa[of][tf] = MFMA16(afr[of], bfr[tf], fa[of][tf]);
    }
    __syncthreads();   // done reading attn frags -> sh0 reusable as staging

    // ---- stage fa as f16 [256 rows][64 t], XOR-swizzled in float4 groups ----
    #pragma unroll
    for (int of = 0; of < 4; ++of)
        #pragma unroll
        for (int tf = 0; tf < 4; ++tf)
            #pragma unroll
            for (int r = 0; r < 4; ++r) {
                int row = w * 64 + of * 16 + 4 * g + r;
                int q   = tf * 4 + (li >> 2);
                int qs  = q ^ (4 * g + r);          // row & 15 == 4g + r
                sh0[row * 64 + qs * 4 + (li & 3)] = (_Float16)fa[of][tf][r];
            }
    __syncthreads();

    // ---- coalesced epilogue: residual add, store, per-channel partial stats ----
    for (int it = 0; it < 16; ++it) {
        int flat = it * 256 + tid;
        int row = flat >> 4, q = flat & 15;
        half4_ hv = *(const half4_*)&sh0[row * 64 + ((q ^ (row & 15)) << 2)];
        float4_ xres = *(const float4_*)&xba[(size_t)row * NSP + q * 4];
        float4_ y;
        float s = 0.f, s2 = 0.f;
        #pragma unroll
        for (int e = 0; e < 4; ++e) {
            y[e] = (float)hv[e] + xres[e];
            s += y[e];
            s2 = fmaf(y[e], y[e], s2);
        }
        *(float4_*)&rba[(size_t)row * NSP + q * 4] = y;
        #pragma unroll
        for (int off = 1; off < 16; off <<= 1) {
            s  += __shfl_xor(s, off);
            s2 += __shfl_xor(s2, off);
        }
        if ((tid & 15) == 0) {
            atomicAdd(&stat[(by * CI + row) * 2],     s);
            atomicAdd(&stat[(by * CI + row) * 2 + 1], s2);
        }
    }
}

// ---------------------------------------------------------------------------
// norm: single-pass InstanceNorm + affine + SiLU using precomputed stats.
// ---------------------------------------------------------------------------
__global__ __launch_bounds__(256) void norm_kernel(
    float* __restrict__ rout, const float* __restrict__ nw,
    const float* __restrict__ nb, const float* __restrict__ stat)
{
    int blk = blockIdx.x;              // b*256 + c
    int c = blk & 255;
    float S  = stat[blk * 2];
    float S2 = stat[blk * 2 + 1];
    float mu = S * (1.0f / (float)NSP);
    float var = S2 * (1.0f / (float)NSP) - mu * mu;
    float rstd = rsqrtf(var + 1e-5f);
    float gg = nw[c] * rstd;
    float b2 = fmaf(-mu, gg, nb[c]);
    float4_* row4 = (float4_*)(rout + (size_t)blk * NSP);
    for (int i = threadIdx.x; i < NSP / 4; i += 256) {
        float4_ v = row4[i];
        #pragma unroll
        for (int u = 0; u < 4; ++u) {
            float y = fmaf(v[u], gg, b2);
            v[u] = y / (1.f + __expf(-y));
        }
        row4[i] = v;
    }
}

// ---------------------------------------------------------------------------
extern "C" void kernel_launch(void* const* d_in, const int* in_sizes, int n_in,
                              void* d_out, int out_size, void* d_ws, size_t ws_size,
                              hipStream_t stream) {
    const float* x_img = (const float*)d_in[0];
    const float* x_txt = (const float*)d_in[1];
    const void*  tmask = d_in[2];
    const float* qpw   = (const float*)d_in[3];
    const float* kpw   = (const float*)d_in[4];
    const float* vpw   = (const float*)d_in[5];
    const float* iqw   = (const float*)d_in[6];
    const float* iqb   = (const float*)d_in[7];
    const float* ikw   = (const float*)d_in[8];
    const float* ikb   = (const float*)d_in[9];
    const float* ivw   = (const float*)d_in[10];
    const float* ivb   = (const float*)d_in[11];
    const float* opw   = (const float*)d_in[12];
    const float* opb   = (const float*)d_in[13];
    const float* ocw   = (const float*)d_in[14];
    const float* ocb   = (const float*)d_in[15];
    const float* nw    = (const float*)d_in[16];
    const float* nb    = (const float*)d_in[17];
    float* ws  = (float*)d_ws;
    float* out = (float*)d_out;

    prep_kernel<<<3, 256, 0, stream>>>(opb, ocw, ocb, iqb, tmask, ws);
    wcomb_kernel<<<128, 256, 0, stream>>>(qpw, iqw, opw, ocw, kpw, ikw, vpw, ivw, ws);
    kv_kernel<<<16, 256, 0, stream>>>(x_txt, ws, ikb, ivb);
    main_kernel<<<dim3(NTILE, B_), 256, 0, stream>>>(x_img, ws, out, ws + OFF_STAT);
    norm_kernel<<<B_ * CI, 256, 0, stream>>>(out, nw, nb, ws + OFF_STAT);
}

// Round 9
// 460.298 us; speedup vs baseline: 2.9790x; 1.0962x over previous
//
#include <hip/hip_runtime.h>
#include <cstdint>
#include <cstddef>

// Problem constants
#define B_    8
#define CI    256
#define NH    8
#define HD    32
#define LQ    77
#define LP    80
#define NSP   13824   // 24^3
#define NTILE 216     // 13824 / 64
#define SCALE 0.17677669529663687f   // 1/sqrt(32)

typedef float    float4_ __attribute__((ext_vector_type(4)));
typedef _Float16 half4_  __attribute__((ext_vector_type(4)));

#define MFMA16(a,b,c) __builtin_amdgcn_mfma_f32_16x16x16f16((a),(b),(c),0,0,0)

// Workspace layout (float offsets) — total 427,136 floats ~= 1.71 MB.
// (R5 lesson: a 5.25 MB layout corrupted memory past ws_size; stay <= ~1.7 MB proven.)
// Fragment conventions (verified R2/R4 passing kernels):
//  A-frag of M[row][k]:  a[j] at lane = M[row = lane&15][k = 4*(lane>>4)+j]
//  B-frag of M[k][col]:  b[j] at lane = M[k = 4*(lane>>4)+j][col = lane&15]
//  D-frag:               d[r] at lane = D[row = 4*(lane>>4)+r][col = lane&15]
//  => D-frag of T^T == A-frag of T ;  A-frag of M == B-frag of M^T
#define OFF_WQP  0                        // Wq A-frags [16kt][16ot][64][4] f16 (pre-scaled)
#define OFF_WOP  32768                    // Wo A-frags [16][16][64][4] f16
#define OFF_WKP  65536                    // Wk A-frags [48kt][16ot][64][4] f16
#define OFF_WVP  163840                   // Wv A-frags [48][16][64][4] f16
#define OFF_KP   262144                   // K  A-frags [B][H][5lt][2kd][64][4] f16
#define OFF_VP   344064                   // V' A-frags [B][H][2dt][5lt][64][4] f16
#define OFF_BO   425984                   // 256 f32 combined out bias
#define OFF_IQBS 426240                   // 256 f32 in_q bias * SCALE
#define OFF_AM   426496                   // 8x80 f32 additive mask

// ---------------------------------------------------------------------------
// wcomb (+prep): combined weights via MFMA -> A-frag f16 layout; biases; mask.
//   T[o][k] = sum_m iw[o][m] * pw[m][k];  D = T^T via A~(pw^T) x B~(iw^T);
//   D-frag of T^T == A-frag of T -> contiguous half4 store.
// blk<16 Wq, <32 Wo, <80 Wk, <128 Wv, ==128 biases, ==129 mask.
// ---------------------------------------------------------------------------
__global__ __launch_bounds__(256) void wcomb_kernel(
    const float* __restrict__ qpw, const float* __restrict__ iqw,
    const float* __restrict__ opw, const float* __restrict__ ocw,
    const float* __restrict__ kpw, const float* __restrict__ ikw,
    const float* __restrict__ vpw, const float* __restrict__ ivw,
    const float* __restrict__ opb, const float* __restrict__ ocb,
    const float* __restrict__ iqb, const void* __restrict__ mask_in,
    float* __restrict__ ws)
{
    int blk = blockIdx.x, tid = threadIdx.x;

    if (blk >= 128) {
        if (blk == 128) {
            // bo = ocw@opb + ocb ; iqbs = iqb*SCALE
            float a = ocb[tid];
            const float* row = ocw + tid * 256;
            #pragma unroll 4
            for (int m = 0; m < 256; ++m) a = fmaf(row[m], opb[m], a);
            ws[OFF_BO + tid] = a;
            ws[OFF_IQBS + tid] = iqb[tid] * SCALE;
        } else {
            // additive mask, with bool int8/int32 detection
            __shared__ int s_is8;
            if (tid == 0) s_is8 = 0;
            __syncthreads();
            const unsigned char* m8 = (const unsigned char*)mask_in;
            for (int i = tid; i < B_ * LQ; i += 256)
                if ((i & 3) && m8[i]) atomicExch(&s_is8, 1);
            __syncthreads();
            int is8 = s_is8;
            const int* mi = (const int*)mask_in;
            float* mo = ws + OFF_AM;
            for (int i = tid; i < B_ * LP; i += 256) {
                int b = i / LP, l = i % LP;
                int v = 1;
                if (l < LQ) v = is8 ? (int)m8[b * LQ + l] : mi[b * LQ + l];
                mo[i] = v ? -1e30f : 0.0f;
            }
        }
        return;
    }

    int lane = tid & 63, w = tid >> 6, g = lane >> 4, li = lane & 15;
    const float *iw, *pw; _Float16* dst; int pstride, ctb, otb; float scale = 1.f;
    if (blk < 16) {
        iw = iqw; pw = qpw; pstride = 256; dst = (_Float16*)(ws + OFF_WQP);
        ctb = blk >> 2; otb = blk & 3; scale = SCALE;
    } else if (blk < 32) {
        int j = blk - 16;
        iw = ocw; pw = opw; pstride = 256; dst = (_Float16*)(ws + OFF_WOP);
        ctb = j >> 2; otb = j & 3;
    } else if (blk < 80) {
        int j = blk - 32;
        iw = ikw; pw = kpw; pstride = 768; dst = (_Float16*)(ws + OFF_WKP);
        ctb = j >> 2; otb = j & 3;
    } else {
        int j = blk - 80;
        iw = ivw; pw = vpw; pstride = 768; dst = (_Float16*)(ws + OFF_WVP);
        ctb = j >> 2; otb = j & 3;
    }
    int ct = ctb * 4 + w;      // output-k tile handled by this wave

    float4_ acc[4];
    #pragma unroll
    for (int i = 0; i < 4; ++i)
        #pragma unroll
        for (int r = 0; r < 4; ++r) acc[i][r] = 0.f;

    for (int mt = 0; mt < 16; ++mt) {
        half4_ ah;
        #pragma unroll
        for (int j = 0; j < 4; ++j)
            ah[j] = (_Float16)pw[(size_t)(mt * 16 + 4 * g + j) * pstride + ct * 16 + li];
        #pragma unroll
        for (int i = 0; i < 4; ++i) {
            int o = (otb * 4 + i) * 16 + li;
            float4_ bw = *(const float4_*)&iw[(size_t)o * 256 + mt * 16 + 4 * g];
            half4_ bh;
            #pragma unroll
            for (int j = 0; j < 4; ++j) bh[j] = (_Float16)bw[j];
            acc[i] = MFMA16(ah, bh, acc[i]);
        }
    }
    #pragma unroll
    for (int i = 0; i < 4; ++i) {
        half4_ oh;
        #pragma unroll
        for (int r = 0; r < 4; ++r) oh[r] = (_Float16)(acc[i][r] * scale);
        *(half4_*)&dst[((size_t)(ct * 16 + otb * 4 + i) * 64 + lane) * 4] = oh;
    }
}

// ---------------------------------------------------------------------------
// kv: kh/vh via MFMA directly into K/V fragment layouts.
//   K-part: D = Wk x X^T (rows=o, cols=l) -> A-frag of kh[l][d]
//   V-part: D = X x Wv^T (rows=l, cols=o) -> A-frag of vh^T = V'[d][l]
// Grid: (b, part) = 16 blocks, 4 waves; wave w -> ot in [4w, 4w+4).
// ---------------------------------------------------------------------------
__global__ __launch_bounds__(256) void kv_kernel(
    const float* __restrict__ xtxt, float* __restrict__ ws,
    const float* __restrict__ ikb, const float* __restrict__ ivb)
{
    const _Float16* wkA = (const _Float16*)(ws + OFF_WKP);
    const _Float16* wvA = (const _Float16*)(ws + OFF_WVP);
    _Float16* kp = (_Float16*)(ws + OFF_KP);
    _Float16* vp = (_Float16*)(ws + OFF_VP);

    int b = blockIdx.x >> 1, part = blockIdx.x & 1;
    int tid = threadIdx.x, lane = tid & 63, w = tid >> 6, g = lane >> 4, li = lane & 15;

    float4_ acc[4][5];
    if (part == 0) {
        #pragma unroll
        for (int i = 0; i < 4; ++i) {
            float4_ bias = *(const float4_*)&ikb[(w * 4 + i) * 16 + 4 * g];
            #pragma unroll
            for (int lt = 0; lt < 5; ++lt) acc[i][lt] = bias;
        }
    } else {
        #pragma unroll
        for (int i = 0; i < 4; ++i) {
            float bv = ivb[(w * 4 + i) * 16 + li];
            #pragma unroll
            for (int lt = 0; lt < 5; ++lt)
                #pragma unroll
                for (int r = 0; r < 4; ++r) acc[i][lt][r] = bv;
        }
    }

    for (int kt = 0; kt < 48; ++kt) {
        half4_ xh[5];
        #pragma unroll
        for (int lt = 0; lt < 5; ++lt) {
            int l = lt * 16 + li;
            float4_ xv = {0.f, 0.f, 0.f, 0.f};
            if (l < LQ)
                xv = *(const float4_*)&xtxt[(size_t)(b * LQ + l) * 768 + kt * 16 + 4 * g];
            #pragma unroll
            for (int j = 0; j < 4; ++j) xh[lt][j] = (_Float16)xv[j];
        }
        if (part == 0) {
            #pragma unroll
            for (int i = 0; i < 4; ++i) {
                half4_ aw = *(const half4_*)&wkA[((size_t)(kt * 16 + w * 4 + i) * 64 + lane) * 4];
                #pragma unroll
                for (int lt = 0; lt < 5; ++lt)
                    acc[i][lt] = MFMA16(aw, xh[lt], acc[i][lt]);
            }
        } else {
            #pragma unroll
            for (int i = 0; i < 4; ++i) {
                half4_ bw = *(const half4_*)&wvA[((size_t)(kt * 16 + w * 4 + i) * 64 + lane) * 4];
                #pragma unroll
                for (int lt = 0; lt < 5; ++lt)
                    acc[i][lt] = MFMA16(xh[lt], bw, acc[i][lt]);
            }
        }
    }

    #pragma unroll
    for (int i = 0; i < 4; ++i) {
        int ot = w * 4 + i, h = ot >> 1;
        size_t hb = (size_t)(b * NH + h) * 10;
        #pragma unroll
        for (int lt = 0; lt < 5; ++lt) {
            half4_ oh;
            #pragma unroll
            for (int r = 0; r < 4; ++r) oh[r] = (_Float16)acc[i][lt][r];
            if (part == 0) {
                int kd = ot & 1;
                *(half4_*)&kp[(hb + lt * 2 + kd) * 256 + lane * 4] = oh;
            } else {
                int dt = ot & 1;
                *(half4_*)&vp[(hb + dt * 5 + lt) * 256 + lane * 4] = oh;
            }
        }
    }
}

// ---------------------------------------------------------------------------
// main: stage X frags -> qh GEMM (regs) -> attention (reg-chained, tf-split)
//  -> out GEMM -> LDS-staged coalesced epilogue (residual). No atomics.
// Block 256 = 4 waves, 4 blocks/CU. Wave w owns output channels [w*64, w*64+64).
// ---------------------------------------------------------------------------
__global__ __launch_bounds__(256, 4) void main_kernel(
    const float* __restrict__ x_img, const float* __restrict__ ws,
    float* __restrict__ rout)
{
    const _Float16* wqpk = (const _Float16*)(ws + OFF_WQP);
    const _Float16* wopk = (const _Float16*)(ws + OFF_WOP);
    const _Float16* kpck = (const _Float16*)(ws + OFF_KP);
    const _Float16* vpck = (const _Float16*)(ws + OFF_VP);
    const float* iqbs = ws + OFF_IQBS;
    const float* bog  = ws + OFF_BO;

    __shared__ _Float16 sh0[16384];
    __shared__ float am_s[LP];

    const int tid  = threadIdx.x;
    const int lane = tid & 63;
    const int w    = __builtin_amdgcn_readfirstlane(tid >> 6);
    const int g    = lane >> 4;
    const int li   = lane & 15;
    const int by   = blockIdx.y;
    const int bx   = blockIdx.x;
    const int n0   = bx * 64;

    const float* xba = x_img + (size_t)by * CI * NSP + n0;
    float*       rba = rout  + (size_t)by * CI * NSP + n0;

    if (tid < LP) am_s[tid] = ws[OFF_AM + by * LP + tid];

    // ---- stage X tile as B-frags (float4 coalesced loads, scalar f16 LDS writes) ----
    for (int it = 0; it < 16; ++it) {
        int idx = it * 256 + tid;           // 0..4095
        int c = idx >> 4, t4 = (idx & 15) * 4;
        float4_ xv = *(const float4_*)&xba[(size_t)c * NSP + t4];
        int kt = c >> 4, lhi = 16 * ((c >> 2) & 3), jj = c & 3;
        #pragma unroll
        for (int u = 0; u < 4; ++u) {
            int t = t4 + u;
            sh0[((kt * 4 + (t >> 4)) * 64 + (t & 15) + lhi) * 4 + jj] = (_Float16)xv[u];
        }
    }
    __syncthreads();

    // ---- phase 1: qh = Wq @ X + iqb; accumulators stay in registers ----
    half4_ qh_h[4][4];
    {
        float4_ acc[4][4];
        #pragma unroll
        for (int of = 0; of < 4; ++of) {
            float4_ bias = *(const float4_*)&iqbs[w * 64 + of * 16 + 4 * g];
            #pragma unroll
            for (int tf = 0; tf < 4; ++tf) acc[of][tf] = bias;
        }
        for (int kt = 0; kt < 16; ++kt) {
            half4_ bfr[4], afr[4];
            #pragma unroll
            for (int tf = 0; tf < 4; ++tf)
                bfr[tf] = *(const half4_*)&sh0[((kt * 4 + tf) * 64 + lane) * 4];
            #pragma unroll
            for (int of = 0; of < 4; ++of)
                afr[of] = *(const half4_*)&wqpk[((size_t)(kt * 16 + w * 4 + of) * 64 + lane) * 4];
            #pragma unroll
            for (int of = 0; of < 4; ++of)
                #pragma unroll
                for (int tf = 0; tf < 4; ++tf)
                    acc[of][tf] = MFMA16(afr[of], bfr[tf], acc[of][tf]);
        }
        #pragma unroll
        for (int of = 0; of < 4; ++of)
            #pragma unroll
            for (int tf = 0; tf < 4; ++tf)
                #pragma unroll
                for (int r = 0; r < 4; ++r)
                    qh_h[of][tf][r] = (_Float16)acc[of][tf][r];
    }
    __syncthreads();   // all waves done reading X frags -> sh0 reusable

    // ---- phase 2: attention, wave w handles heads 2w, 2w+1 (tf-halved) ----
    #pragma unroll
    for (int hh = 0; hh < 2; ++hh) {
        const int h = 2 * w + hh;
        const _Float16* kp = kpck + (size_t)(by * NH + h) * 2560;
        const _Float16* vp = vpck + (size_t)(by * NH + h) * 2560;
        float mk[5][4];
        #pragma unroll
        for (int lt = 0; lt < 5; ++lt)
            #pragma unroll
            for (int r = 0; r < 4; ++r) mk[lt][r] = am_s[lt * 16 + 4 * g + r];
        #pragma unroll
        for (int tfh = 0; tfh < 2; ++tfh) {
            float4_ sc[5][2];
            #pragma unroll
            for (int lt = 0; lt < 5; ++lt)
                #pragma unroll
                for (int t2 = 0; t2 < 2; ++t2)
                    #pragma unroll
                    for (int r = 0; r < 4; ++r) sc[lt][t2][r] = 0.f;
            #pragma unroll
            for (int lt = 0; lt < 5; ++lt)
                #pragma unroll
                for (int kd = 0; kd < 2; ++kd) {
                    half4_ akf = *(const half4_*)&kp[((lt * 2 + kd) * 64 + lane) * 4];
                    #pragma unroll
                    for (int t2 = 0; t2 < 2; ++t2)
                        sc[lt][t2] = MFMA16(akf, qh_h[2 * hh + kd][tfh * 2 + t2], sc[lt][t2]);
                }
            #pragma unroll
            for (int lt = 0; lt < 5; ++lt)
                #pragma unroll
                for (int t2 = 0; t2 < 2; ++t2)
                    #pragma unroll
                    for (int r = 0; r < 4; ++r) sc[lt][t2][r] += mk[lt][r];
            // softmax over l (rows)
            float inv[2];
            #pragma unroll
            for (int t2 = 0; t2 < 2; ++t2) {
                float m = -3.0e38f;
                #pragma unroll
                for (int lt = 0; lt < 5; ++lt)
                    #pragma unroll
                    for (int r = 0; r < 4; ++r) m = fmaxf(m, sc[lt][t2][r]);
                m = fmaxf(m, __shfl_xor(m, 16));
                m = fmaxf(m, __shfl_xor(m, 32));
                float s = 0.f;
                #pragma unroll
                for (int lt = 0; lt < 5; ++lt)
                    #pragma unroll
                    for (int r = 0; r < 4; ++r) {
                        float e = __expf(sc[lt][t2][r] - m);
                        sc[lt][t2][r] = e;
                        s += e;
                    }
                s += __shfl_xor(s, 16);
                s += __shfl_xor(s, 32);
                inv[t2] = 1.0f / s;
            }
            // PV (P frags chained from sc)
            float4_ oa[2][2];
            #pragma unroll
            for (int dt = 0; dt < 2; ++dt)
                #pragma unroll
                for (int t2 = 0; t2 < 2; ++t2)
                    #pragma unroll
                    for (int r = 0; r < 4; ++r) oa[dt][t2][r] = 0.f;
            #pragma unroll
            for (int lt = 0; lt < 5; ++lt) {
                half4_ pl[2];
                #pragma unroll
                for (int t2 = 0; t2 < 2; ++t2)
                    #pragma unroll
                    for (int r = 0; r < 4; ++r) pl[t2][r] = (_Float16)sc[lt][t2][r];
                #pragma unroll
                for (int dt = 0; dt < 2; ++dt) {
                    half4_ avf = *(const half4_*)&vp[((dt * 5 + lt) * 64 + lane) * 4];
                    #pragma unroll
                    for (int t2 = 0; t2 < 2; ++t2)
                        oa[dt][t2] = MFMA16(avf, pl[t2], oa[dt][t2]);
                }
            }
            // normalize + store attn-out frags to sh0
            #pragma unroll
            for (int dt = 0; dt < 2; ++dt)
                #pragma unroll
                for (int t2 = 0; t2 < 2; ++t2) {
                    half4_ ov;
                    #pragma unroll
                    for (int r = 0; r < 4; ++r) ov[r] = (_Float16)(oa[dt][t2][r] * inv[t2]);
                    *(half4_*)&sh0[(((h * 2 + dt) * 4 + tfh * 2 + t2) * 64 + lane) * 4] = ov;
                }
        }
    }
    __syncthreads();

    // ---- phase 3: r_pre = Wo @ attn_out + bo ----
    float4_ fa[4][4];
    #pragma unroll
    for (int of = 0; of < 4; ++of) {
        float4_ bias = *(const float4_*)&bog[w * 64 + of * 16 + 4 * g];
        #pragma unroll
        for (int tf = 0; tf < 4; ++tf) fa[of][tf] = bias;
    }
    for (int kt = 0; kt < 16; ++kt) {
        half4_ bfr[4], afr[4];
        #pragma unroll
        for (int tf = 0; tf < 4; ++tf)
            bfr[tf] = *(const half4_*)&sh0[((kt * 4 + tf) * 64 + lane) * 4];
        #pragma unroll
        for (int of = 0; of < 4; ++of)
            afr[of] = *(const half4_*)&wopk[((size_t)(kt * 16 + w * 4 + of) * 64 + lane) * 4];
        #pragma unroll
        for (int of = 0; of < 4; ++of)
            #pragma unroll
            for (int tf = 0; tf < 4; ++tf)
                fa[of][tf] = MFMA16(afr[of], bfr[tf], fa[of][tf]);
    }
    __syncthreads();   // done reading attn frags -> sh0 reusable as staging

    // ---- stage fa as f16 [256 rows][64 t], XOR-swizzled in float4 groups ----
    #pragma unroll
    for (int of = 0; of < 4; ++of)
        #pragma unroll
        for (int tf = 0; tf < 4; ++tf)
            #pragma unroll
            for (int r = 0; r < 4; ++r) {
                int row = w * 64 + of * 16 + 4 * g + r;
                int q   = tf * 4 + (li >> 2);
                int qs  = q ^ (4 * g + r);          // row & 15 == 4g + r
                sh0[row * 64 + qs * 4 + (li & 3)] = (_Float16)fa[of][tf][r];
            }
    __syncthreads();

    // ---- coalesced epilogue: residual add + full-line stores ----
    for (int it = 0; it < 16; ++it) {
        int flat = it * 256 + tid;
        int row = flat >> 4, q = flat & 15;
        half4_ hv = *(const half4_*)&sh0[row * 64 + ((q ^ (row & 15)) << 2)];
        float4_ xres = *(const float4_*)&xba[(size_t)row * NSP + q * 4];
        float4_ y;
        #pragma unroll
        for (int e = 0; e < 4; ++e) y[e] = (float)hv[e] + xres[e];
        *(float4_*)&rba[(size_t)row * NSP + q * 4] = y;
    }
}

// ---------------------------------------------------------------------------
// norm: per-(b,c) InstanceNorm + affine + SiLU, in place, two-pass (R2-proven).
// Second pass re-reads the 55 KB row mostly from L2.
// ---------------------------------------------------------------------------
__global__ __launch_bounds__(256) void norm_kernel(
    float* __restrict__ rout, const float* __restrict__ nw, const float* __restrict__ nb)
{
    __shared__ float red[8];
    __shared__ float stats[2];
    int blk = blockIdx.x;              // b*256 + c
    int c = blk & 255;
    float* row = rout + (size_t)blk * NSP;
    float4_* row4 = (float4_*)row;
    int tid = threadIdx.x;

    float s = 0.f, s2 = 0.f;
    for (int i = tid; i < NSP / 4; i += 256) {
        float4_ v = row4[i];
        #pragma unroll
        for (int u = 0; u < 4; ++u) { s += v[u]; s2 = fmaf(v[u], v[u], s2); }
    }
    #pragma unroll
    for (int off = 32; off > 0; off >>= 1) {
        s  += __shfl_down(s, off);
        s2 += __shfl_down(s2, off);
    }
    int wv = tid >> 6, ln = tid & 63;
    if (ln == 0) { red[wv] = s; red[4 + wv] = s2; }
    __syncthreads();
    if (tid == 0) {
        float S  = red[0] + red[1] + red[2] + red[3];
        float S2 = red[4] + red[5] + red[6] + red[7];
        float mu = S * (1.0f / (float)NSP);
        float var = S2 * (1.0f / (float)NSP) - mu * mu;
        stats[0] = mu;
        stats[1] = rsqrtf(var + 1e-5f);
    }
    __syncthreads();
    float mu = stats[0], rstd = stats[1];
    float gg = nw[c] * rstd;
    float b2 = fmaf(-mu, gg, nb[c]);
    for (int i = tid; i < NSP / 4; i += 256) {
        float4_ v = row4[i];
        #pragma unroll
        for (int u = 0; u < 4; ++u) {
            float y = fmaf(v[u], gg, b2);
            v[u] = y / (1.f + __expf(-y));
        }
        row4[i] = v;
    }
}

// ---------------------------------------------------------------------------
extern "C" void kernel_launch(void* const* d_in, const int* in_sizes, int n_in,
                              void* d_out, int out_size, void* d_ws, size_t ws_size,
                              hipStream_t stream) {
    const float* x_img = (const float*)d_in[0];
    const float* x_txt = (const float*)d_in[1];
    const void*  tmask = d_in[2];
    const float* qpw   = (const float*)d_in[3];
    const float* kpw   = (const float*)d_in[4];
    const float* vpw   = (const float*)d_in[5];
    const float* iqw   = (const float*)d_in[6];
    const float* iqb   = (const float*)d_in[7];
    const float* ikw   = (const float*)d_in[8];
    const float* ikb   = (const float*)d_in[9];
    const float* ivw   = (const float*)d_in[10];
    const float* ivb   = (const float*)d_in[11];
    const float* opw   = (const float*)d_in[12];
    const float* opb   = (const float*)d_in[13];
    const float* ocw   = (const float*)d_in[14];
    const float* ocb   = (const float*)d_in[15];
    const float* nw    = (const float*)d_in[16];
    const float* nb    = (const float*)d_in[17];
    float* ws  = (float*)d_ws;
    float* out = (float*)d_out;

    wcomb_kernel<<<130, 256, 0, stream>>>(qpw, iqw, opw, ocw, kpw, ikw, vpw, ivw,
                                          opb, ocb, iqb, tmask, ws);
    kv_kernel<<<16, 256, 0, stream>>>(x_txt, ws, ikb, ivb);
    main_kernel<<<dim3(NTILE, B_), 256, 0, stream>>>(x_img, ws, out);
    norm_kernel<<<B_ * CI, 256, 0, stream>>>(out, nw, nb);
}